// Round 5
// baseline (210.327 us; speedup 1.0000x reference)
//
#include <hip/hip_runtime.h>

typedef short bf16x8 __attribute__((ext_vector_type(8)));
typedef float f32x4 __attribute__((ext_vector_type(4)));

__device__ __forceinline__ float b2f(unsigned short s) {
    union { float f; unsigned u; } x; x.u = ((unsigned)s) << 16; return x.f;
}
__device__ __forceinline__ unsigned short f2b(float f) {
    unsigned u = __float_as_uint(f);
    unsigned r = (u + 0x7fffu + ((u >> 16) & 1u)) >> 16;
    return (unsigned short)r;
}

// ---------------- cast f32 weights / point-features -> bf16 workspace ----------------
// dst layout: [ciw 32768][qw 49152][pw 16384][ow 16384][cw 32768][ptsf 1048576]
__global__ __launch_bounds__(256) void cast_k(const float* __restrict__ ciw,
                                              const float* __restrict__ qw,
                                              const float* __restrict__ pw,
                                              const float* __restrict__ ow,
                                              const float* __restrict__ cw,
                                              const float* __restrict__ ptsf,
                                              unsigned short* __restrict__ dst) {
    int i = blockIdx.x * 256 + threadIdx.x;
    float v;
    if (i < 32768)        v = ciw[i];
    else if (i < 81920)   v = qw[i - 32768];
    else if (i < 98304)   v = pw[i - 81920];
    else if (i < 114688)  v = ow[i - 98304];
    else if (i < 147456)  v = cw[i - 114688];
    else                  v = ptsf[i - 147456];
    dst[i] = f2b(v);
}

// ---------------- transpose+cast: in[b][c][hw] (f32) -> A_rm[p=b*4096+hw][c] (bf16) ----
__global__ __launch_bounds__(256) void transpose_k(const float* __restrict__ in,
                                                   unsigned short* __restrict__ out) {
    __shared__ unsigned short t[64][65];
    int p0 = blockIdx.x * 64, c0 = blockIdx.y * 64, b = blockIdx.z;
    int lane = threadIdx.x & 63, quad = threadIdx.x >> 6;
#pragma unroll
    for (int i = 0; i < 16; ++i) {
        int c = quad + i * 4;
        t[c][lane] = f2b(in[((size_t)(b * 256 + c0 + c)) * 4096 + p0 + lane]);
    }
    __syncthreads();
#pragma unroll
    for (int i = 0; i < 16; ++i) {
        int p = quad + i * 4;
        out[((size_t)(b * 4096 + p0 + p)) * 256 + c0 + lane] = t[lane][p];
    }
}

// ---------------- window bookkeeping ----------------
__global__ void zero_k(int* cnt) { cnt[threadIdx.x] = 0; }

__global__ __launch_bounds__(256) void assign_k(const int* __restrict__ uv,
                                                int* __restrict__ cnt,
                                                int* __restrict__ wpts) {
    int i = blockIdx.x * 256 + threadIdx.x;
    if (i >= 8192) return;
    int b = uv[3 * i] & 1;
    int u = uv[3 * i + 1] & 63;
    int v = uv[3 * i + 2] & 63;
    int w = b * 64 + ((v >> 3) << 3) + (u >> 3);
    int slot = atomicAdd(cnt + w, 1);
    if (slot < 192) wpts[w * 192 + slot] = i;
}

// ---------------- generic MFMA GEMM: C[M][N] = A[M][K] * W[N][K]^T + bias ----------------
// MODE 0: bf16 row-major store; MODE 1: f32 row-major store; MODE 2: bchw f32 store.
// A1 (if non-null) supplies rows >= 8192 (qkv: pixel feat + point feat).
template<int K, int MODE>
__global__ __launch_bounds__(256) void gemm_k(const unsigned short* __restrict__ A0,
                                              const unsigned short* __restrict__ A1,
                                              const unsigned short* __restrict__ Wm,
                                              const float* __restrict__ bias,
                                              void* __restrict__ Cv, int ldc) {
    int lane = threadIdx.x & 63;
    int wv = threadIdx.x >> 6;
    int m0 = (blockIdx.x * 4 + wv) * 16;
    int q = lane & 15, g = lane >> 4;
    const unsigned short* Arow;
    {
        int row = m0 + q;
        Arow = (A1 != nullptr && row >= 8192) ? (A1 + (size_t)(row - 8192) * K)
                                              : (A0 + (size_t)row * K);
    }
    int nb = blockIdx.y * 64;
    int koff = g * 8;
    f32x4 acc[4];
#pragma unroll
    for (int t = 0; t < 4; ++t) acc[t] = (f32x4){0.f, 0.f, 0.f, 0.f};
#pragma unroll
    for (int k0 = 0; k0 < K; k0 += 32) {
        bf16x8 a = *(const bf16x8*)(Arow + k0 + koff);
#pragma unroll
        for (int t = 0; t < 4; ++t) {
            const unsigned short* wr = Wm + (size_t)(nb + t * 16 + q) * K + k0 + koff;
            bf16x8 bfr = *(const bf16x8*)wr;
            acc[t] = __builtin_amdgcn_mfma_f32_16x16x32_bf16(a, bfr, acc[t], 0, 0, 0);
        }
    }
#pragma unroll
    for (int t = 0; t < 4; ++t) {
        int n = nb + t * 16 + q;
        float bs = bias[n];
        if constexpr (MODE == 2) {
            int p = m0 + g * 4;
            float4 pk;
            pk.x = acc[t][0] + bs;
            pk.y = acc[t][1] + bs;
            pk.z = acc[t][2] + bs;
            pk.w = acc[t][3] + bs;
            size_t ad = ((size_t)((p >> 12) * 256 + n)) * 4096 + (size_t)(p & 4095);
            *(float4*)((float*)Cv + ad) = pk;
        } else {
#pragma unroll
            for (int rr = 0; rr < 4; ++rr) {
                float v = acc[t][rr] + bs;
                int row = m0 + g * 4 + rr;
                if constexpr (MODE == 0)
                    ((unsigned short*)Cv)[(size_t)row * ldc + n] = f2b(v);
                else
                    ((float*)Cv)[(size_t)row * ldc + n] = v;
            }
        }
    }
}

// ---------------- windowed attention (queries = 64 pixels/window) ----------------
// grid = 512 blocks: (window w = blk>>2, head-pair hh = blk&3); 128 threads = 2 waves,
// wave i handles head hh*2+i. One lane = one query (pixel). K/V bf16 in LDS.
__global__ __launch_bounds__(128) void attn_k(const unsigned short* __restrict__ qkv,
                                              const int* __restrict__ cnt,
                                              const int* __restrict__ wpts,
                                              unsigned short* __restrict__ aout) {
    __shared__ unsigned short Kl[256][32];
    __shared__ unsigned short Vl[256][32];
    int blk = blockIdx.x;
    int w = blk >> 2, hh = blk & 3;
    int b = w >> 6, wy = (w >> 3) & 7, wx = w & 7;
    int tid = threadIdx.x, wave = tid >> 6, lane = tid & 63;
    int c = cnt[w]; if (c > 192) c = 192;
    int T = 64 + c;
    {
        int part = tid & 3;
        for (int s = tid >> 2; s < T; s += 32) {
            int tok;
            if (s < 64) tok = b * 4096 + (wy * 8 + (s >> 3)) * 64 + wx * 8 + (s & 7);
            else        tok = 8192 + wpts[w * 192 + s - 64];
            const unsigned short* base = qkv + (size_t)tok * 384 + hh * 32 + part * 8;
            *(bf16x8*)&Kl[s][part * 8] = *(const bf16x8*)(base + 128);
            *(bf16x8*)&Vl[s][part * 8] = *(const bf16x8*)(base + 256);
        }
    }
    __syncthreads();
    int head = hh * 2 + wave;
    int qrow = b * 4096 + (wy * 8 + (lane >> 3)) * 64 + wx * 8 + (lane & 7);
    const unsigned short* qp = qkv + (size_t)qrow * 384 + head * 16;
    bf16x8 q0 = *(const bf16x8*)qp;
    bf16x8 q1 = *(const bf16x8*)(qp + 8);
    float qf[16];
#pragma unroll
    for (int i = 0; i < 8; ++i) {
        qf[i] = b2f((unsigned short)q0[i]);
        qf[8 + i] = b2f((unsigned short)q1[i]);
    }
    float mval = -3.0e38f, lsum = 0.f;
    float av[16];
#pragma unroll
    for (int i = 0; i < 16; ++i) av[i] = 0.f;
    int ho = wave * 16;
    for (int j = 0; j < T; ++j) {
        bf16x8 kk0 = *(const bf16x8*)&Kl[j][ho];
        bf16x8 kk1 = *(const bf16x8*)&Kl[j][ho + 8];
        float s_ = 0.f;
#pragma unroll
        for (int i = 0; i < 8; ++i) {
            s_ += qf[i] * b2f((unsigned short)kk0[i]);
            s_ += qf[8 + i] * b2f((unsigned short)kk1[i]);
        }
        s_ *= 0.25f;
        float nm = fmaxf(mval, s_);
        if (nm > mval) {
            float f_ = __expf(mval - nm);
            lsum *= f_;
#pragma unroll
            for (int i = 0; i < 16; ++i) av[i] *= f_;
            mval = nm;
        }
        float p = __expf(s_ - mval);
        lsum += p;
        bf16x8 vv0 = *(const bf16x8*)&Vl[j][ho];
        bf16x8 vv1 = *(const bf16x8*)&Vl[j][ho + 8];
#pragma unroll
        for (int i = 0; i < 8; ++i) {
            av[i] += p * b2f((unsigned short)vv0[i]);
            av[8 + i] += p * b2f((unsigned short)vv1[i]);
        }
    }
    float inv = 1.0f / lsum;
    bf16x8 o0, o1;
#pragma unroll
    for (int i = 0; i < 8; ++i) {
        o0[i] = (short)f2b(av[i] * inv);
        o1[i] = (short)f2b(av[8 + i] * inv);
    }
    unsigned short* op = aout + (size_t)qrow * 128 + head * 16;
    *(bf16x8*)op = o0;
    *(bf16x8*)(op + 8) = o1;
}

// ---------------- fused RK4 ODE (row-independent): imgf = RK4(img0) + img0, bf16 out ----
// 128 threads = 2 waves; each wave owns 16 rows. W in LDS; state in registers (C-frag layout).
__global__ __launch_bounds__(128) void ode_k(const float* __restrict__ img,
                                             const unsigned short* __restrict__ Wg,
                                             const float* __restrict__ bg,
                                             unsigned short* __restrict__ outimg) {
    __shared__ unsigned short Wl[128][136];
    __shared__ unsigned short tc[2][16][136];
    int tid = threadIdx.x, wave = tid >> 6, lane = tid & 63;
    int g = lane >> 4, q = lane & 15;
    {
        int part = tid & 15;
#pragma unroll
        for (int it = 0; it < 16; ++it) {
            int rr = (tid >> 4) + it * 8;
            *(bf16x8*)&Wl[rr][part * 8] = *(const bf16x8*)(Wg + rr * 128 + part * 8);
        }
    }
    int R0 = blockIdx.x * 32 + wave * 16;
    float bs[8];
#pragma unroll
    for (int tn = 0; tn < 8; ++tn) bs[tn] = bg[tn * 16 + q];
    float y[32], acc[32], ko[32];
#pragma unroll
    for (int tn = 0; tn < 8; ++tn)
#pragma unroll
        for (int rr = 0; rr < 4; ++rr)
            y[tn * 4 + rr] = img[(size_t)(R0 + g * 4 + rr) * 128 + tn * 16 + q];

#define WRITE_TC(EXPR)                                            \
    {                                                             \
        _Pragma("unroll")                                         \
        for (int tn = 0; tn < 8; ++tn) {                          \
            _Pragma("unroll")                                     \
            for (int rr = 0; rr < 4; ++rr) {                      \
                int i_ = tn * 4 + rr;                             \
                tc[wave][g * 4 + rr][tn * 16 + q] = f2b(EXPR);    \
            }                                                     \
        }                                                         \
        __syncthreads();                                          \
    }

#define EVAL()                                                                         \
    {                                                                                  \
        bf16x8 af[4];                                                                  \
        _Pragma("unroll")                                                              \
        for (int tk = 0; tk < 4; ++tk)                                                 \
            af[tk] = *(const bf16x8*)&tc[wave][q][tk * 32 + g * 8];                    \
        _Pragma("unroll")                                                              \
        for (int tn = 0; tn < 8; ++tn) {                                               \
            f32x4 cc = (f32x4){0.f, 0.f, 0.f, 0.f};                                    \
            _Pragma("unroll")                                                          \
            for (int tk = 0; tk < 4; ++tk) {                                           \
                bf16x8 bfr = *(const bf16x8*)&Wl[tn * 16 + q][tk * 32 + g * 8];        \
                cc = __builtin_amdgcn_mfma_f32_16x16x32_bf16(af[tk], bfr, cc, 0, 0, 0);\
            }                                                                          \
            _Pragma("unroll")                                                          \
            for (int rr = 0; rr < 4; ++rr)                                             \
                ko[tn * 4 + rr] = fmaxf(cc[rr] + bs[tn], 0.f);                         \
        }                                                                              \
    }

    WRITE_TC(y[i_])
    const float dt = 0.25f;
    for (int st = 0; st < 4; ++st) {
        EVAL();
#pragma unroll
        for (int i = 0; i < 32; ++i) acc[i] = y[i] + (dt / 6.f) * ko[i];
        WRITE_TC(y[i_] + (0.5f * dt) * ko[i_])
        EVAL();
#pragma unroll
        for (int i = 0; i < 32; ++i) acc[i] += (dt / 3.f) * ko[i];
        WRITE_TC(y[i_] + (0.5f * dt) * ko[i_])
        EVAL();
#pragma unroll
        for (int i = 0; i < 32; ++i) acc[i] += (dt / 3.f) * ko[i];
        WRITE_TC(y[i_] + dt * ko[i_])
        EVAL();
#pragma unroll
        for (int i = 0; i < 32; ++i) y[i] = acc[i] + (dt / 6.f) * ko[i];
        WRITE_TC(y[i_])
    }
#pragma unroll
    for (int tn = 0; tn < 8; ++tn)
#pragma unroll
        for (int rr = 0; rr < 4; ++rr) {
            size_t idx = (size_t)(R0 + g * 4 + rr) * 128 + tn * 16 + q;
            outimg[idx] = f2b(y[tn * 4 + rr] + img[idx]);
        }
#undef WRITE_TC
#undef EVAL
}

extern "C" void kernel_launch(void* const* d_in, const int* in_sizes, int n_in,
                              void* d_out, int out_size, void* d_ws, size_t ws_size,
                              hipStream_t stream) {
    (void)in_sizes; (void)n_in; (void)out_size; (void)ws_size;
    const float* img_in = (const float*)d_in[0];
    const int*   pts_uv = (const int*)d_in[1];
    const float* ptsf   = (const float*)d_in[2];
    const float* ciw    = (const float*)d_in[3];
    const float* cib    = (const float*)d_in[4];
    const float* qw     = (const float*)d_in[5];
    const float* qb     = (const float*)d_in[6];
    const float* pw     = (const float*)d_in[7];
    const float* pb     = (const float*)d_in[8];
    const float* ow     = (const float*)d_in[9];
    const float* ob     = (const float*)d_in[10];
    const float* cw     = (const float*)d_in[11];
    const float* cb     = (const float*)d_in[12];

    char* ws = (char*)d_ws;
    unsigned short* Arm  = (unsigned short*)(ws);                 // 8192x256 bf16 = 4 MiB
    unsigned short* feat = (unsigned short*)(ws + 4194304);       // 8192x128 bf16 = 2 MiB
    unsigned short* qkv  = (unsigned short*)(ws + 6291456);       // 16384x384 bf16 = 12 MiB
    unsigned short* aout = (unsigned short*)(ws + 18874368);      // 8192x128 bf16 = 2 MiB
    float*          img0 = (float*)(ws + 20971520);               // 8192x128 f32 = 4 MiB
    unsigned short* imgf = (unsigned short*)(ws + 25165824);      // 8192x128 bf16 = 2 MiB
    int*            cnt  = (int*)(ws + 27262976);                 // 128 ints
    int*            wpts = (int*)(ws + 27263488);                 // 128x192 ints
    unsigned short* wb   = (unsigned short*)(ws + 27787264);      // bf16 weights+ptsf, 2.28 MiB
    unsigned short* ciw_b = wb;
    unsigned short* qw_b  = wb + 32768;
    unsigned short* pw_b  = wb + 81920;
    unsigned short* ow_b  = wb + 98304;
    unsigned short* cw_b  = wb + 114688;
    unsigned short* ptsf_b= wb + 147456;

    cast_k<<<4672, 256, 0, stream>>>(ciw, qw, pw, ow, cw, ptsf, wb);
    transpose_k<<<dim3(64, 4, 2), 256, 0, stream>>>(img_in, Arm);
    zero_k<<<1, 128, 0, stream>>>(cnt);
    assign_k<<<32, 256, 0, stream>>>(pts_uv, cnt, wpts);
    gemm_k<256, 0><<<dim3(128, 2), 256, 0, stream>>>(Arm, nullptr, ciw_b, cib, feat, 128);
    gemm_k<128, 0><<<dim3(256, 6), 256, 0, stream>>>(feat, ptsf_b, qw_b, qb, qkv, 384);
    attn_k<<<512, 128, 0, stream>>>(qkv, cnt, wpts, aout);
    gemm_k<128, 1><<<dim3(128, 2), 256, 0, stream>>>(aout, nullptr, pw_b, pb, img0, 128);
    ode_k<<<256, 128, 0, stream>>>(img0, ow_b, ob, imgf);
    gemm_k<128, 2><<<dim3(128, 4), 256, 0, stream>>>(imgf, nullptr, cw_b, cb, d_out, 0);
}

// Round 6
// 170.544 us; speedup vs baseline: 1.2333x; 1.2333x over previous
//
#include <hip/hip_runtime.h>

typedef short bf16x8 __attribute__((ext_vector_type(8)));
typedef float f32x4 __attribute__((ext_vector_type(4)));

__device__ __forceinline__ float b2f(unsigned short s) {
    union { float f; unsigned u; } x; x.u = ((unsigned)s) << 16; return x.f;
}
__device__ __forceinline__ unsigned short f2b(float f) {
    unsigned u = __float_as_uint(f);
    unsigned r = (u + 0x7fffu + ((u >> 16) & 1u)) >> 16;
    return (unsigned short)r;
}

// ---------------- cast f32 weights / point-features -> bf16 workspace ----------------
// dst layout: [ciw 32768][qw 49152][pw 16384][ow 16384][cw 32768][ptsf 1048576]
// Also zeroes the window-count buffer (runs before assign_k on the stream).
__global__ __launch_bounds__(256) void cast_k(const float* __restrict__ ciw,
                                              const float* __restrict__ qw,
                                              const float* __restrict__ pw,
                                              const float* __restrict__ ow,
                                              const float* __restrict__ cw,
                                              const float* __restrict__ ptsf,
                                              unsigned short* __restrict__ dst,
                                              int* __restrict__ cnt) {
    if (blockIdx.x == 0 && threadIdx.x < 128) cnt[threadIdx.x] = 0;
    int i = blockIdx.x * 256 + threadIdx.x;
    float v;
    if (i < 32768)        v = ciw[i];
    else if (i < 81920)   v = qw[i - 32768];
    else if (i < 98304)   v = pw[i - 81920];
    else if (i < 114688)  v = ow[i - 98304];
    else if (i < 147456)  v = cw[i - 114688];
    else                  v = ptsf[i - 147456];
    dst[i] = f2b(v);
}

// ---------------- transpose+cast: in[b][c][hw] (f32) -> A_rm[p=b*4096+hw][c] (bf16) ----
__global__ __launch_bounds__(256) void transpose_k(const float* __restrict__ in,
                                                   unsigned short* __restrict__ out) {
    __shared__ unsigned short t[64][65];
    int p0 = blockIdx.x * 64, c0 = blockIdx.y * 64, b = blockIdx.z;
    int lane = threadIdx.x & 63, quad = threadIdx.x >> 6;
#pragma unroll
    for (int i = 0; i < 16; ++i) {
        int c = quad + i * 4;
        t[c][lane] = f2b(in[((size_t)(b * 256 + c0 + c)) * 4096 + p0 + lane]);
    }
    __syncthreads();
#pragma unroll
    for (int i = 0; i < 16; ++i) {
        int p = quad + i * 4;
        out[((size_t)(b * 4096 + p0 + p)) * 256 + c0 + lane] = t[lane][p];
    }
}

// ---------------- window bookkeeping ----------------
__global__ __launch_bounds__(256) void assign_k(const int* __restrict__ uv,
                                                int* __restrict__ cnt,
                                                int* __restrict__ wpts) {
    int i = blockIdx.x * 256 + threadIdx.x;
    if (i >= 8192) return;
    int b = uv[3 * i] & 1;
    int u = uv[3 * i + 1] & 63;
    int v = uv[3 * i + 2] & 63;
    int w = b * 64 + ((v >> 3) << 3) + (u >> 3);
    int slot = atomicAdd(cnt + w, 1);
    if (slot < 192) wpts[w * 192 + slot] = i;
}

// ---------------- generic MFMA GEMM: C[M][N] = A[M][K] * W[N][K]^T + bias ----------------
// MODE 0: bf16 row-major store; MODE 1: f32 row-major store; MODE 2: bchw f32 store.
// A1 (if non-null) supplies rows >= 8192 (qkv: pixel feat + point feat).
template<int K, int MODE>
__global__ __launch_bounds__(256) void gemm_k(const unsigned short* __restrict__ A0,
                                              const unsigned short* __restrict__ A1,
                                              const unsigned short* __restrict__ Wm,
                                              const float* __restrict__ bias,
                                              void* __restrict__ Cv, int ldc) {
    int lane = threadIdx.x & 63;
    int wv = threadIdx.x >> 6;
    int m0 = (blockIdx.x * 4 + wv) * 16;
    int q = lane & 15, g = lane >> 4;
    const unsigned short* Arow;
    {
        int row = m0 + q;
        Arow = (A1 != nullptr && row >= 8192) ? (A1 + (size_t)(row - 8192) * K)
                                              : (A0 + (size_t)row * K);
    }
    int nb = blockIdx.y * 64;
    int koff = g * 8;
    f32x4 acc[4];
#pragma unroll
    for (int t = 0; t < 4; ++t) acc[t] = (f32x4){0.f, 0.f, 0.f, 0.f};
#pragma unroll
    for (int k0 = 0; k0 < K; k0 += 32) {
        bf16x8 a = *(const bf16x8*)(Arow + k0 + koff);
#pragma unroll
        for (int t = 0; t < 4; ++t) {
            const unsigned short* wr = Wm + (size_t)(nb + t * 16 + q) * K + k0 + koff;
            bf16x8 bfr = *(const bf16x8*)wr;
            acc[t] = __builtin_amdgcn_mfma_f32_16x16x32_bf16(a, bfr, acc[t], 0, 0, 0);
        }
    }
#pragma unroll
    for (int t = 0; t < 4; ++t) {
        int n = nb + t * 16 + q;
        float bs = bias[n];
        if constexpr (MODE == 2) {
            int p = m0 + g * 4;
            float4 pk;
            pk.x = acc[t][0] + bs;
            pk.y = acc[t][1] + bs;
            pk.z = acc[t][2] + bs;
            pk.w = acc[t][3] + bs;
            size_t ad = ((size_t)((p >> 12) * 256 + n)) * 4096 + (size_t)(p & 4095);
            *(float4*)((float*)Cv + ad) = pk;
        } else {
#pragma unroll
            for (int rr = 0; rr < 4; ++rr) {
                float v = acc[t][rr] + bs;
                int row = m0 + g * 4 + rr;
                if constexpr (MODE == 0)
                    ((unsigned short*)Cv)[(size_t)row * ldc + n] = f2b(v);
                else
                    ((float*)Cv)[(size_t)row * ldc + n] = v;
            }
        }
    }
}

// ---------------- MFMA windowed attention ----------------
// grid = 1024 blocks: (window w = blk>>3, head h = blk&7); 256 threads = 4 waves,
// wave = one 16-query tile. Swapped-operand MFMA: S^T = mfma(K,Q) -> lane holds
// col=query(l&15), rows=tokens(g*4+r per 16-tile). Softmax reduce = regs + shfl_xor(16,32).
// PV: O^T = mfma(V^T, P) with P k-chunks redistributed via cvt_pk_bf16 + shfl.
__global__ __launch_bounds__(256) void attn_k(const unsigned short* __restrict__ qkv,
                                              const int* __restrict__ cnt,
                                              const int* __restrict__ wpts,
                                              unsigned short* __restrict__ aout) {
    __shared__ unsigned short Kl[256][24];   // [token][dim0..15], stride 48B (16B-aligned)
    __shared__ unsigned short Vt[16][264];   // [dim][token], stride 528B (16B-aligned)
    int blk = blockIdx.x;
    int w = blk >> 3, h = blk & 7;
    int b = w >> 6, wy = (w >> 3) & 7, wx = w & 7;
    int tid = threadIdx.x, wave = tid >> 6, lane = tid & 63;
    int q = lane & 15, g = lane >> 4;
    int c = cnt[w]; if (c > 192) c = 192;
    int T = 64 + c;

    // ---- stage K[t][d], V^T[d][t]; zero-fill t >= T (prevents NaN in PV tail) ----
    {
        int t = tid;  // 256 threads -> 256 token slots
        if (t < T) {
            int tok;
            if (t < 64) tok = b * 4096 + (wy * 8 + (t >> 3)) * 64 + wx * 8 + (t & 7);
            else        tok = 8192 + wpts[w * 192 + t - 64];
            const unsigned short* base = qkv + (size_t)tok * 384 + h * 16;
            bf16x8 k0 = *(const bf16x8*)(base + 128);
            bf16x8 v0 = *(const bf16x8*)(base + 256);
            *(bf16x8*)&Kl[t][0] = k0;
#pragma unroll
            for (int d = 0; d < 8; ++d) Vt[d][t] = (unsigned short)v0[d];
            bf16x8 k1 = *(const bf16x8*)(base + 136);
            bf16x8 v1 = *(const bf16x8*)(base + 264);
            *(bf16x8*)&Kl[t][8] = k1;
#pragma unroll
            for (int d = 0; d < 8; ++d) Vt[8 + d][t] = (unsigned short)v1[d];
        } else {
            bf16x8 z;
#pragma unroll
            for (int d = 0; d < 8; ++d) z[d] = 0;
            *(bf16x8*)&Kl[t][0] = z;
            *(bf16x8*)&Kl[t][8] = z;
#pragma unroll
            for (int d = 0; d < 16; ++d) Vt[d][t] = 0;
        }
    }

    // ---- Q fragment (B operand): row = query l&15, k-chunk g: dims g*8+j, zero for g>=2 ----
    int qq = wave * 16 + q;
    int qrow = b * 4096 + (wy * 8 + (qq >> 3)) * 64 + wx * 8 + (qq & 7);
    bf16x8 qfrag;
#pragma unroll
    for (int j = 0; j < 8; ++j) qfrag[j] = 0;
    if (g < 2) qfrag = *(const bf16x8*)(qkv + (size_t)qrow * 384 + h * 16 + g * 8);

    __syncthreads();

    // ---- S^T = mfma(K, Q): per 16-token tile, lane gets tokens mt*16+g*4+r for query q ----
    float p[16][4];
    int MT = (T + 15) >> 4;
#pragma unroll
    for (int mt = 0; mt < 16; ++mt) {
        if (mt < MT) {
            bf16x8 af = *(const bf16x8*)&Kl[mt * 16 + q][(g & 1) * 8];
            f32x4 cc = (f32x4){0.f, 0.f, 0.f, 0.f};
            cc = __builtin_amdgcn_mfma_f32_16x16x32_bf16(af, qfrag, cc, 0, 0, 0);
#pragma unroll
            for (int r = 0; r < 4; ++r) {
                int tok = mt * 16 + g * 4 + r;
                p[mt][r] = (tok < T) ? cc[r] * 0.25f : -1e30f;
            }
        } else {
#pragma unroll
            for (int r = 0; r < 4; ++r) p[mt][r] = -1e30f;
        }
    }

    // ---- softmax over tokens: local + butterfly over the 4 g-groups ----
    float mv = -3.0e38f;
#pragma unroll
    for (int mt = 0; mt < 16; ++mt)
#pragma unroll
        for (int r = 0; r < 4; ++r) mv = fmaxf(mv, p[mt][r]);
    mv = fmaxf(mv, __shfl_xor(mv, 16));
    mv = fmaxf(mv, __shfl_xor(mv, 32));
    float ls = 0.f;
#pragma unroll
    for (int mt = 0; mt < 16; ++mt)
#pragma unroll
        for (int r = 0; r < 4; ++r) {
            float e = __expf(p[mt][r] - mv);
            p[mt][r] = e;
            ls += e;
        }
    ls += __shfl_xor(ls, 16);
    ls += __shfl_xor(ls, 32);

    // ---- O^T = mfma(V^T, P) over 32-token k-steps ----
    f32x4 oacc = (f32x4){0.f, 0.f, 0.f, 0.f};
    int KS = (T + 31) >> 5;
    int srcA = q + (((2 * g) & 3) << 4);
    int srcB = q + (((2 * g + 1) & 3) << 4);
#pragma unroll
    for (int ks = 0; ks < 8; ++ks) {
        if (ks < KS) {
            int n0lo, n0hi, n1lo, n1hi;
            asm("v_cvt_pk_bf16_f32 %0, %1, %2" : "=v"(n0lo) : "v"(p[2 * ks][0]), "v"(p[2 * ks][1]));
            asm("v_cvt_pk_bf16_f32 %0, %1, %2" : "=v"(n0hi) : "v"(p[2 * ks][2]), "v"(p[2 * ks][3]));
            asm("v_cvt_pk_bf16_f32 %0, %1, %2" : "=v"(n1lo) : "v"(p[2 * ks + 1][0]), "v"(p[2 * ks + 1][1]));
            asm("v_cvt_pk_bf16_f32 %0, %1, %2" : "=v"(n1hi) : "v"(p[2 * ks + 1][2]), "v"(p[2 * ks + 1][3]));
            int a0 = __shfl(n0lo, srcA), b0 = __shfl(n1lo, srcA);
            int a1 = __shfl(n0hi, srcA), b1 = __shfl(n1hi, srcA);
            int a2 = __shfl(n0lo, srcB), b2 = __shfl(n1lo, srcB);
            int a3 = __shfl(n0hi, srcB), b3 = __shfl(n1hi, srcB);
            union { int d[4]; bf16x8 v; } pb;
            bool lo2 = (g < 2);
            pb.d[0] = lo2 ? a0 : b0;
            pb.d[1] = lo2 ? a1 : b1;
            pb.d[2] = lo2 ? a2 : b2;
            pb.d[3] = lo2 ? a3 : b3;
            bf16x8 vf = *(const bf16x8*)&Vt[q][ks * 32 + g * 8];
            oacc = __builtin_amdgcn_mfma_f32_16x16x32_bf16(vf, pb.v, oacc, 0, 0, 0);
        }
    }

    // ---- store: lane holds O[dims g*4+r][query q] ----
    float inv = 1.0f / ls;
    ushort4 st;
    st.x = f2b(oacc[0] * inv);
    st.y = f2b(oacc[1] * inv);
    st.z = f2b(oacc[2] * inv);
    st.w = f2b(oacc[3] * inv);
    *(ushort4*)(aout + (size_t)qrow * 128 + h * 16 + g * 4) = st;
}

// ---------------- fused RK4 ODE (row-independent): imgf = RK4(img0) + img0, bf16 out ----
// 128 threads = 2 waves; each wave owns 16 rows. W in LDS; state in registers (C-frag layout).
__global__ __launch_bounds__(128) void ode_k(const float* __restrict__ img,
                                             const unsigned short* __restrict__ Wg,
                                             const float* __restrict__ bg,
                                             unsigned short* __restrict__ outimg) {
    __shared__ unsigned short Wl[128][136];
    __shared__ unsigned short tc[2][16][136];
    int tid = threadIdx.x, wave = tid >> 6, lane = tid & 63;
    int g = lane >> 4, q = lane & 15;
    {
        int part = tid & 15;
#pragma unroll
        for (int it = 0; it < 16; ++it) {
            int rr = (tid >> 4) + it * 8;
            *(bf16x8*)&Wl[rr][part * 8] = *(const bf16x8*)(Wg + rr * 128 + part * 8);
        }
    }
    int R0 = blockIdx.x * 32 + wave * 16;
    float bs[8];
#pragma unroll
    for (int tn = 0; tn < 8; ++tn) bs[tn] = bg[tn * 16 + q];
    float y[32], acc[32], ko[32];
#pragma unroll
    for (int tn = 0; tn < 8; ++tn)
#pragma unroll
        for (int rr = 0; rr < 4; ++rr)
            y[tn * 4 + rr] = img[(size_t)(R0 + g * 4 + rr) * 128 + tn * 16 + q];

#define WRITE_TC(EXPR)                                            \
    {                                                             \
        _Pragma("unroll")                                         \
        for (int tn = 0; tn < 8; ++tn) {                          \
            _Pragma("unroll")                                     \
            for (int rr = 0; rr < 4; ++rr) {                      \
                int i_ = tn * 4 + rr;                             \
                tc[wave][g * 4 + rr][tn * 16 + q] = f2b(EXPR);    \
            }                                                     \
        }                                                         \
        __syncthreads();                                          \
    }

#define EVAL()                                                                         \
    {                                                                                  \
        bf16x8 af[4];                                                                  \
        _Pragma("unroll")                                                              \
        for (int tk = 0; tk < 4; ++tk)                                                 \
            af[tk] = *(const bf16x8*)&tc[wave][q][tk * 32 + g * 8];                    \
        _Pragma("unroll")                                                              \
        for (int tn = 0; tn < 8; ++tn) {                                               \
            f32x4 cc = (f32x4){0.f, 0.f, 0.f, 0.f};                                    \
            _Pragma("unroll")                                                          \
            for (int tk = 0; tk < 4; ++tk) {                                           \
                bf16x8 bfr = *(const bf16x8*)&Wl[tn * 16 + q][tk * 32 + g * 8];        \
                cc = __builtin_amdgcn_mfma_f32_16x16x32_bf16(af[tk], bfr, cc, 0, 0, 0);\
            }                                                                          \
            _Pragma("unroll")                                                          \
            for (int rr = 0; rr < 4; ++rr)                                             \
                ko[tn * 4 + rr] = fmaxf(cc[rr] + bs[tn], 0.f);                         \
        }                                                                              \
    }

    WRITE_TC(y[i_])
    const float dt = 0.25f;
    for (int st = 0; st < 4; ++st) {
        EVAL();
#pragma unroll
        for (int i = 0; i < 32; ++i) acc[i] = y[i] + (dt / 6.f) * ko[i];
        WRITE_TC(y[i_] + (0.5f * dt) * ko[i_])
        EVAL();
#pragma unroll
        for (int i = 0; i < 32; ++i) acc[i] += (dt / 3.f) * ko[i];
        WRITE_TC(y[i_] + (0.5f * dt) * ko[i_])
        EVAL();
#pragma unroll
        for (int i = 0; i < 32; ++i) acc[i] += (dt / 3.f) * ko[i];
        WRITE_TC(y[i_] + dt * ko[i_])
        EVAL();
#pragma unroll
        for (int i = 0; i < 32; ++i) y[i] = acc[i] + (dt / 6.f) * ko[i];
        WRITE_TC(y[i_])
    }
#pragma unroll
    for (int tn = 0; tn < 8; ++tn)
#pragma unroll
        for (int rr = 0; rr < 4; ++rr) {
            size_t idx = (size_t)(R0 + g * 4 + rr) * 128 + tn * 16 + q;
            outimg[idx] = f2b(y[tn * 4 + rr] + img[idx]);
        }
#undef WRITE_TC
#undef EVAL
}

extern "C" void kernel_launch(void* const* d_in, const int* in_sizes, int n_in,
                              void* d_out, int out_size, void* d_ws, size_t ws_size,
                              hipStream_t stream) {
    (void)in_sizes; (void)n_in; (void)out_size; (void)ws_size;
    const float* img_in = (const float*)d_in[0];
    const int*   pts_uv = (const int*)d_in[1];
    const float* ptsf   = (const float*)d_in[2];
    const float* ciw    = (const float*)d_in[3];
    const float* cib    = (const float*)d_in[4];
    const float* qw     = (const float*)d_in[5];
    const float* qb     = (const float*)d_in[6];
    const float* pw     = (const float*)d_in[7];
    const float* pb     = (const float*)d_in[8];
    const float* ow     = (const float*)d_in[9];
    const float* ob     = (const float*)d_in[10];
    const float* cw     = (const float*)d_in[11];
    const float* cb     = (const float*)d_in[12];

    char* ws = (char*)d_ws;
    unsigned short* Arm  = (unsigned short*)(ws);                 // 8192x256 bf16 = 4 MiB
    unsigned short* feat = (unsigned short*)(ws + 4194304);       // 8192x128 bf16 = 2 MiB
    unsigned short* qkv  = (unsigned short*)(ws + 6291456);       // 16384x384 bf16 = 12 MiB
    unsigned short* aout = (unsigned short*)(ws + 18874368);      // 8192x128 bf16 = 2 MiB
    float*          img0 = (float*)(ws + 20971520);               // 8192x128 f32 = 4 MiB
    unsigned short* imgf = (unsigned short*)(ws + 25165824);      // 8192x128 bf16 = 2 MiB
    int*            cnt  = (int*)(ws + 27262976);                 // 128 ints
    int*            wpts = (int*)(ws + 27263488);                 // 128x192 ints
    unsigned short* wb   = (unsigned short*)(ws + 27787264);      // bf16 weights+ptsf, 2.28 MiB
    unsigned short* ciw_b = wb;
    unsigned short* qw_b  = wb + 32768;
    unsigned short* pw_b  = wb + 81920;
    unsigned short* ow_b  = wb + 98304;
    unsigned short* cw_b  = wb + 114688;
    unsigned short* ptsf_b= wb + 147456;

    cast_k<<<4672, 256, 0, stream>>>(ciw, qw, pw, ow, cw, ptsf, wb, cnt);
    transpose_k<<<dim3(64, 4, 2), 256, 0, stream>>>(img_in, Arm);
    assign_k<<<32, 256, 0, stream>>>(pts_uv, cnt, wpts);
    gemm_k<256, 0><<<dim3(128, 2), 256, 0, stream>>>(Arm, nullptr, ciw_b, cib, feat, 128);
    gemm_k<128, 0><<<dim3(256, 6), 256, 0, stream>>>(feat, ptsf_b, qw_b, qb, qkv, 384);
    attn_k<<<1024, 256, 0, stream>>>(qkv, cnt, wpts, aout);
    gemm_k<128, 1><<<dim3(128, 2), 256, 0, stream>>>(aout, nullptr, pw_b, pb, img0, 128);
    ode_k<<<256, 128, 0, stream>>>(img0, ow_b, ob, imgf);
    gemm_k<128, 2><<<dim3(128, 4), 256, 0, stream>>>(imgf, nullptr, cw_b, cb, d_out, 0);
}